// Round 4
// baseline (34.696 us; speedup 1.0000x reference)
//
#include <hip/hip_runtime.h>
#include <hip/hip_bf16.h>
#include <hip/hip_cooperative_groups.h>

namespace cg = cooperative_groups;

// ZeroOneLoss: out = mean_i( input[i, targets[i]] > 0 ),  B=16384, V=32000.
//
// Single cooperative dispatch (1 graph node):
//   64 blocks x 256 threads gather one row each (spread over 64 CUs so the
//   16384 scattered HBM loads are one ~1us latency shot -- R2 lesson),
//   per-block int partial -> d_ws, grid.sync(), block 0 reduces the 64
//   partials and overwrites d_out. No memset node needed (plain store, not
//   accumulate), no atomics -> deterministic across graph replays.
//
// Fallback (if cooperative launch is unavailable): R3's 2-node scheme
// (memset d_out + ballot/atomicAdd of exact multiples of 2^-14).

__global__ void zol_coop(const float* __restrict__ input,
                         const int* __restrict__ targets,
                         float* __restrict__ out,
                         int* __restrict__ partials,
                         int B, long long V) {
    const int i = blockIdx.x * blockDim.x + threadIdx.x;
    bool pred = false;
    if (i < B) {
        int t = targets[i];
        pred = input[(long long)i * V + (long long)t] > 0.0f;
    }
    unsigned long long m = __ballot(pred);

    __shared__ int wsum[4];                     // 256 threads = 4 waves
    const int lane = threadIdx.x & 63;
    const int wid = threadIdx.x >> 6;
    if (lane == 0) wsum[wid] = (int)__popcll(m);
    __syncthreads();
    if (threadIdx.x == 0)
        partials[blockIdx.x] = wsum[0] + wsum[1] + wsum[2] + wsum[3];

    cg::this_grid().sync();

    if (blockIdx.x == 0 && threadIdx.x < 64) {
        int v = 0;
        for (int j = threadIdx.x; j < (int)gridDim.x; j += 64)
            v += partials[j];
        #pragma unroll
        for (int off = 32; off > 0; off >>= 1)
            v += __shfl_down(v, off, 64);
        if (threadIdx.x == 0)
            out[0] = (float)v / (float)B;
    }
}

// ---- fallback path (2 nodes) ----
__global__ void zol_gather_atomic(const float* __restrict__ input,
                                  const int* __restrict__ targets,
                                  float* __restrict__ out,
                                  int B, long long V, float invB) {
    int i = blockIdx.x * blockDim.x + threadIdx.x;
    bool pred = false;
    if (i < B) {
        int t = targets[i];
        pred = input[(long long)i * V + (long long)t] > 0.0f;
    }
    unsigned long long m = __ballot(pred);
    if ((threadIdx.x & 63) == 0) {
        int c = (int)__popcll(m);
        if (c) atomicAdd(out, (float)c * invB);
    }
}

extern "C" void kernel_launch(void* const* d_in, const int* in_sizes, int n_in,
                              void* d_out, int out_size, void* d_ws, size_t ws_size,
                              hipStream_t stream) {
    const float* input = (const float*)d_in[0];
    const int* targets = (const int*)d_in[1];
    float* out = (float*)d_out;

    int B = in_sizes[1];                                         // 16384
    long long V = (long long)in_sizes[0] / (long long)B;         // 32000
    int* partials = (int*)d_ws;

    const int block = 256;
    dim3 grid((B + block - 1) / block);                          // 64 blocks

    void* args[] = { (void*)&input, (void*)&targets, (void*)&out,
                     (void*)&partials, (void*)&B, (void*)&V };
    hipError_t err = hipLaunchCooperativeKernel((const void*)zol_coop,
                                                grid, dim3(block),
                                                args, 0, stream);
    if (err != hipSuccess) {
        hipMemsetAsync(out, 0, sizeof(float), stream);
        zol_gather_atomic<<<grid, block, 0, stream>>>(input, targets, out,
                                                      B, V, 1.0f / (float)B);
    }
}

// Round 5
// 12.046 us; speedup vs baseline: 2.8803x; 2.8803x over previous
//
#include <hip/hip_runtime.h>
#include <hip/hip_bf16.h>

// ZeroOneLoss: out = mean_i( input[i, targets[i]] > 0 ),  B=16384, V=32000.
//
// SINGLE regular graph node (R4 showed cooperative-launch-in-graph costs
// ~20us; R3 showed each extra node ~1.1us):
//   blocks 0..63  : gather 256 rows each (spread across CUs -> one HBM
//                   latency shot, R2 lesson), per-block popcount published
//                   as (0x5A5A0000 | count) into flags[b] in d_ws with a
//                   device-scope atomic store (cross-XCD coherent).
//   block 64      : reducer. First wave polls the 64 flags with
//                   device-scope atomic loads until each shows the 0x5A5A
//                   signature, sums the 16-bit partials (exact int sum ->
//                   deterministic), writes out[0], and resets flags to 0
//                   so the next graph replay starts clean.
//
// Safety:
//  - One-way wait (gatherers never wait) -> deadlock-free regardless of
//    dispatch order / co-residency.
//  - Harness poison 0xAAAAAAAA cannot spoof signature 0x5A5Axxxx, so the
//    first post-poison replay is correct; reducer's reset handles the rest.
//  - No atomics into d_out, plain overwrite -> no memset node needed.

#define ZOL_SIG 0x5A5A0000u

__global__ __launch_bounds__(256) void zol_fused(
        const float* __restrict__ input,
        const int* __restrict__ targets,
        float* __restrict__ out,
        unsigned int* __restrict__ flags,
        int B, long long V, int nGather) {
    const int b = blockIdx.x;
    const int tid = threadIdx.x;

    if (b < nGather) {
        // ---- gather block ----
        int i = b * 256 + tid;
        bool pred = false;
        if (i < B) {
            int t = targets[i];
            pred = input[(long long)i * V + (long long)t] > 0.0f;
        }
        unsigned long long m = __ballot(pred);
        __shared__ int wsum[4];
        const int lane = tid & 63, wid = tid >> 6;
        if (lane == 0) wsum[wid] = (int)__popcll(m);
        __syncthreads();
        if (tid == 0) {
            unsigned tot = (unsigned)(wsum[0] + wsum[1] + wsum[2] + wsum[3]);
            __hip_atomic_store(&flags[b], ZOL_SIG | tot,
                               __ATOMIC_RELEASE, __HIP_MEMORY_SCOPE_AGENT);
        }
    } else {
        // ---- reducer block (first wave only) ----
        if (tid < 64) {
            int v = 0;
            for (int j = tid; j < nGather; j += 64) {
                unsigned f;
                do {
                    f = __hip_atomic_load(&flags[j], __ATOMIC_ACQUIRE,
                                          __HIP_MEMORY_SCOPE_AGENT);
                } while ((f & 0xFFFF0000u) != ZOL_SIG);
                v += (int)(f & 0xFFFFu);
                __hip_atomic_store(&flags[j], 0u,
                                   __ATOMIC_RELAXED, __HIP_MEMORY_SCOPE_AGENT);
            }
            #pragma unroll
            for (int off = 32; off > 0; off >>= 1)
                v += __shfl_down(v, off, 64);
            if (tid == 0)
                out[0] = (float)v / (float)B;
        }
    }
}

extern "C" void kernel_launch(void* const* d_in, const int* in_sizes, int n_in,
                              void* d_out, int out_size, void* d_ws, size_t ws_size,
                              hipStream_t stream) {
    const float* input = (const float*)d_in[0];
    const int* targets = (const int*)d_in[1];
    float* out = (float*)d_out;

    const int B = in_sizes[1];                                   // 16384
    const long long V = (long long)in_sizes[0] / (long long)B;   // 32000
    unsigned int* flags = (unsigned int*)d_ws;

    const int nGather = (B + 255) / 256;                         // 64
    zol_fused<<<nGather + 1, 256, 0, stream>>>(input, targets, out, flags,
                                               B, V, nGather);
}